// Round 1
// baseline (792.651 us; speedup 1.0000x reference)
//
#include <hip/hip_runtime.h>
#include <hip/hip_bf16.h>

#define N_PTS 250000
#define N_VOX 60000
#define MID   256
#define KDIM  512
#define NCLS  20
#define BN_EPS 1e-5f

typedef __attribute__((ext_vector_type(8))) short short8;
typedef __attribute__((ext_vector_type(4))) float f32x4;

__device__ __forceinline__ unsigned short f2bf(float f) {
    unsigned u = __builtin_bit_cast(unsigned, f);
    u += 0x7FFFu + ((u >> 16) & 1u);          // round-to-nearest-even
    return (unsigned short)(u >> 16);
}
__device__ __forceinline__ float bf2f(unsigned short h) {
    unsigned u = ((unsigned)h) << 16;
    return __builtin_bit_cast(float, u);
}

// ---------------------------------------------------------------------------
// GEMM1: h[M=250000][256] = concat(point, vox[p2v]) @ W1^T  (+b1)
// bf16 MFMA, fused gather + fp32->bf16 conversion in staging.
// Also accumulates per-column sum / sumsq of h (for BatchNorm) via atomics.
// Tile: 128x128, BK=32, 256 threads = 4 waves (2x2), wave = 4x4 frags 16x16x32.
// LDS rows padded to 40 shorts (80 B): frag-read conflicts are 2-way max (free).
// ---------------------------------------------------------------------------
__global__ __launch_bounds__(256) void gemm1_kernel(
    const float* __restrict__ point, const float* __restrict__ vox,
    const float* __restrict__ W1, const float* __restrict__ b1,
    const int* __restrict__ p2v,
    unsigned short* __restrict__ hbuf,
    float* __restrict__ colsum, float* __restrict__ colsumsq)
{
    __shared__ unsigned short As[128 * 40];
    __shared__ unsigned short Bs[128 * 40];

    const int tid = threadIdx.x;
    const int bN = blockIdx.x;        // 0..1   (MID tiles)
    const int bM = blockIdx.y;        // 0..1953 (row tiles)
    const int r0  = tid >> 3;         // 0..31
    const int off = tid & 7;          // float4 slot within 32-wide k-chunk

    int rA[4]; int vm[4]; int rB[4];
    #pragma unroll
    for (int i = 0; i < 4; ++i) {
        int rg = bM * 128 + r0 + 32 * i;
        if (rg > N_PTS - 1) rg = N_PTS - 1;   // clamp OOB rows (loads only)
        rA[i] = rg;
        vm[i] = p2v[rg];
        rB[i] = bN * 128 + r0 + 32 * i;       // < 256 always
    }

    f32x4 zero4 = {0.f, 0.f, 0.f, 0.f};
    f32x4 acc[4][4];
    #pragma unroll
    for (int mi = 0; mi < 4; ++mi)
        #pragma unroll
        for (int ni = 0; ni < 4; ++ni)
            acc[mi][ni] = zero4;

    const int lane = tid & 63;
    const int wv = tid >> 6;
    const int wm = wv & 1;
    const int wn = wv >> 1;
    const int l15 = lane & 15;
    const int l4  = lane >> 4;

    for (int kt = 0; kt < 16; ++kt) {
        const int kOff = (kt & 7) * 32 + off * 4;
        #pragma unroll
        for (int i = 0; i < 4; ++i) {
            // A: k<256 from point_feature, k>=256 gathered from voxel_feature
            const float* src = (kt < 8)
                ? (point + (size_t)rA[i] * 256 + kOff)
                : (vox   + (size_t)vm[i] * 256 + kOff);
            const float4 v = *(const float4*)src;
            unsigned lo = (unsigned)f2bf(v.x) | ((unsigned)f2bf(v.y) << 16);
            unsigned hi = (unsigned)f2bf(v.z) | ((unsigned)f2bf(v.w) << 16);
            *(uint2*)&As[(r0 + 32 * i) * 40 + off * 4] = make_uint2(lo, hi);

            const float* srcB = W1 + (size_t)rB[i] * 512 + kt * 32 + off * 4;
            const float4 w = *(const float4*)srcB;
            unsigned lo2 = (unsigned)f2bf(w.x) | ((unsigned)f2bf(w.y) << 16);
            unsigned hi2 = (unsigned)f2bf(w.z) | ((unsigned)f2bf(w.w) << 16);
            *(uint2*)&Bs[(r0 + 32 * i) * 40 + off * 4] = make_uint2(lo2, hi2);
        }
        __syncthreads();

        short8 a[4], b[4];
        #pragma unroll
        for (int mi = 0; mi < 4; ++mi)
            a[mi] = *(const short8*)&As[(wm * 64 + mi * 16 + l15) * 40 + l4 * 8];
        #pragma unroll
        for (int ni = 0; ni < 4; ++ni)
            b[ni] = *(const short8*)&Bs[(wn * 64 + ni * 16 + l15) * 40 + l4 * 8];
        #pragma unroll
        for (int mi = 0; mi < 4; ++mi)
            #pragma unroll
            for (int ni = 0; ni < 4; ++ni)
                acc[mi][ni] = __builtin_amdgcn_mfma_f32_16x16x32_bf16(
                                  a[mi], b[ni], acc[mi][ni], 0, 0, 0);
        __syncthreads();
    }

    // Epilogue: +b1, store bf16 h, per-column sum/sumsq partials.
    #pragma unroll
    for (int ni = 0; ni < 4; ++ni) {
        const int colG = bN * 128 + wn * 64 + ni * 16 + l15;
        const float b1v = b1[colG];
        float s = 0.f, sq = 0.f;
        #pragma unroll
        for (int mi = 0; mi < 4; ++mi) {
            const int rgBase = bM * 128 + wm * 64 + mi * 16 + l4 * 4;
            #pragma unroll
            for (int r = 0; r < 4; ++r) {
                const int rr = rgBase + r;
                if (rr < N_PTS) {
                    const float hv = acc[mi][ni][r] + b1v;
                    hbuf[(size_t)rr * 256 + colG] = f2bf(hv);
                    s  += hv;
                    sq += hv * hv;
                }
            }
        }
        // lanes {l15, +16, +32, +48} share colG -> reduce over l4
        s  += __shfl_xor(s, 16);  s  += __shfl_xor(s, 32);
        sq += __shfl_xor(sq, 16); sq += __shfl_xor(sq, 32);
        if (lane < 16) {
            atomicAdd(&colsum[colG], s);
            atomicAdd(&colsumsq[colG], sq);
        }
    }
}

// ---------------------------------------------------------------------------
// BN stats -> per-column scale/shift:  bn(h) = h*scale + shift
// ---------------------------------------------------------------------------
__global__ __launch_bounds__(256) void stats_kernel(
    const float* __restrict__ colsum, const float* __restrict__ colsumsq,
    const float* __restrict__ g1, const float* __restrict__ be1,
    float* __restrict__ scl, float* __restrict__ shf)
{
    const int j = threadIdx.x;
    const float mean = colsum[j] * (1.0f / N_PTS);
    const float var  = colsumsq[j] * (1.0f / N_PTS) - mean * mean;
    const float sc = g1[j] * rsqrtf(var + BN_EPS);
    scl[j] = sc;
    shf[j] = be1[j] - mean * sc;
}

// ---------------------------------------------------------------------------
// cls_acc[c][f] = sum_b softmax(logits)[b][c] * vox[b][f]
// 235 blocks x 4 chunks of 64 voxels; register acc[20] per thread (col f=tid).
// ---------------------------------------------------------------------------
#define NCHUNK 938   // ceil(60000/64)
__global__ __launch_bounds__(256) void cls_acc_kernel(
    const float* __restrict__ logits, const float* __restrict__ vox,
    float* __restrict__ cls_acc)
{
    __shared__ float probs[64 * 24];   // stride 24 floats -> 16B-aligned float4 reads
    const int tid = threadIdx.x;
    float acc[NCLS];
    #pragma unroll
    for (int c = 0; c < NCLS; ++c) acc[c] = 0.f;

    for (int ci = 0; ci < 4; ++ci) {
        const int chunk = blockIdx.x * 4 + ci;
        if (chunk >= NCHUNK) break;            // block-uniform
        const int v0 = chunk * 64;
        __syncthreads();
        if (tid < 64) {
            const int v = v0 + tid;
            if (v < N_VOX) {
                float l[NCLS];
                float mx = -1e30f;
                #pragma unroll
                for (int c = 0; c < NCLS; ++c) {
                    l[c] = logits[(size_t)v * NCLS + c];
                    mx = fmaxf(mx, l[c]);
                }
                float sum = 0.f;
                #pragma unroll
                for (int c = 0; c < NCLS; ++c) { l[c] = __expf(l[c] - mx); sum += l[c]; }
                const float inv = 1.f / sum;
                #pragma unroll
                for (int c = 0; c < NCLS; ++c) probs[tid * 24 + c] = l[c] * inv;
            }
        }
        __syncthreads();
        const int nb = min(64, N_VOX - v0);
        for (int b = 0; b < nb; ++b) {
            const float vv = vox[(size_t)(v0 + b) * 256 + tid];
            #pragma unroll
            for (int c4 = 0; c4 < 5; ++c4) {
                const float4 p = *(const float4*)&probs[b * 24 + c4 * 4];
                acc[c4 * 4 + 0] += p.x * vv;
                acc[c4 * 4 + 1] += p.y * vv;
                acc[c4 * 4 + 2] += p.z * vv;
                acc[c4 * 4 + 3] += p.w * vv;
            }
        }
    }
    #pragma unroll
    for (int c = 0; c < NCLS; ++c)
        atomicAdd(&cls_acc[c * 256 + tid], acc[c]);
}

// ---------------------------------------------------------------------------
// cls_fin = BN_20rows( cls_acc @ W2^T + b2 ).  One block; thread = column m.
// ---------------------------------------------------------------------------
__global__ __launch_bounds__(256) void cls_fea2_kernel(
    const float* __restrict__ cls_acc, const float* __restrict__ W2,
    const float* __restrict__ b2, const float* __restrict__ g2,
    const float* __restrict__ be2, float* __restrict__ cls_fin)
{
    __shared__ float cf[NCLS * 256];
    const int tid = threadIdx.x;
    for (int i = tid; i < NCLS * 256; i += 256) cf[i] = cls_acc[i];
    __syncthreads();

    float acc[NCLS];
    #pragma unroll
    for (int c = 0; c < NCLS; ++c) acc[c] = b2[tid];
    for (int k = 0; k < 256; k += 4) {
        const float4 w = *(const float4*)&W2[(size_t)tid * 256 + k];
        #pragma unroll
        for (int c = 0; c < NCLS; ++c) {
            const float4 f = *(const float4*)&cf[c * 256 + k];
            acc[c] += w.x * f.x + w.y * f.y + w.z * f.z + w.w * f.w;
        }
    }
    float mean = 0.f;
    #pragma unroll
    for (int c = 0; c < NCLS; ++c) mean += acc[c];
    mean *= (1.f / NCLS);
    float var = 0.f;
    #pragma unroll
    for (int c = 0; c < NCLS; ++c) { const float d = acc[c] - mean; var += d * d; }
    var *= (1.f / NCLS);
    const float sc = g2[tid] * rsqrtf(var + BN_EPS);
    const float bb = be2[tid];
    #pragma unroll
    for (int c = 0; c < NCLS; ++c)
        cls_fin[c * 256 + tid] = (acc[c] - mean) * sc + bb;
}

// ---------------------------------------------------------------------------
// GEMM2: out[i][c] = sum_k relu(h[i][k]*scale[k]+shift[k]) * cls_fin[c][k]
// 64 rows/block. x staged in LDS as bf16 stride 258 (reads: stride 129 words,
// conflict-free). cls_fin in LDS, broadcast reads. VALU fp32 accumulate.
// ---------------------------------------------------------------------------
__global__ __launch_bounds__(256) void gemm2_kernel(
    const unsigned short* __restrict__ hbuf,
    const float* __restrict__ scl, const float* __restrict__ shf,
    const float* __restrict__ cls_fin,
    float* __restrict__ out)
{
    __shared__ unsigned short xs[64 * 258];
    __shared__ float cls[NCLS * 256];

    const int tid = threadIdx.x;
    for (int i = tid; i < NCLS * 256; i += 256) cls[i] = cls_fin[i];

    const int rb = blockIdx.x * 64;
    const int rwave = tid >> 6;   // 0..3
    const int c4 = tid & 63;      // 4-col chunk
    const float4 sc4 = *(const float4*)&scl[c4 * 4];
    const float4 sh4 = *(const float4*)&shf[c4 * 4];

    #pragma unroll
    for (int i = 0; i < 16; ++i) {
        const int row = rwave + i * 4;
        const int rg = rb + row;
        ushort4 hv = make_ushort4(0, 0, 0, 0);
        if (rg < N_PTS) hv = *(const ushort4*)&hbuf[(size_t)rg * 256 + c4 * 4];
        const float x0 = fmaxf(bf2f(hv.x) * sc4.x + sh4.x, 0.f);
        const float x1 = fmaxf(bf2f(hv.y) * sc4.y + sh4.y, 0.f);
        const float x2 = fmaxf(bf2f(hv.z) * sc4.z + sh4.z, 0.f);
        const float x3 = fmaxf(bf2f(hv.w) * sc4.w + sh4.w, 0.f);
        ushort4 xv = make_ushort4(f2bf(x0), f2bf(x1), f2bf(x2), f2bf(x3));
        *(ushort4*)&xs[row * 258 + c4 * 4] = xv;
    }
    __syncthreads();

    const int r = tid & 63;       // row within tile (lane)
    const int g = tid >> 6;       // class group: classes g*5 .. g*5+4
    float a[5] = {0.f, 0.f, 0.f, 0.f, 0.f};
    const float* cb = &cls[g * 5 * 256];
    for (int k = 0; k < 256; k += 2) {
        const unsigned xp = *(const unsigned*)&xs[r * 258 + k];
        const float x0 = bf2f((unsigned short)(xp & 0xFFFFu));
        const float x1 = bf2f((unsigned short)(xp >> 16));
        #pragma unroll
        for (int j = 0; j < 5; ++j) {
            const float2 cv = *(const float2*)&cb[j * 256 + k];
            a[j] += x0 * cv.x + x1 * cv.y;
        }
    }
    const int rg = rb + r;
    if (rg < N_PTS) {
        float* o = &out[(size_t)rg * 20 + g * 5];
        #pragma unroll
        for (int j = 0; j < 5; ++j) o[j] = a[j];
    }
}

// ---------------------------------------------------------------------------
extern "C" void kernel_launch(void* const* d_in, const int* in_sizes, int n_in,
                              void* d_out, int out_size, void* d_ws, size_t ws_size,
                              hipStream_t stream)
{
    const float* point  = (const float*)d_in[0];
    const float* vox    = (const float*)d_in[1];
    const float* logits = (const float*)d_in[2];
    const float* W1     = (const float*)d_in[3];
    const float* b1     = (const float*)d_in[4];
    const float* g1     = (const float*)d_in[5];
    const float* be1    = (const float*)d_in[6];
    const float* W2     = (const float*)d_in[7];
    const float* b2     = (const float*)d_in[8];
    const float* g2     = (const float*)d_in[9];
    const float* be2    = (const float*)d_in[10];
    const int*   p2v    = (const int*)d_in[11];
    float* out = (float*)d_out;

    char* ws = (char*)d_ws;
    unsigned short* hbuf = (unsigned short*)ws;
    size_t o = (size_t)N_PTS * 256 * 2;               // 128,000,000 B
    float* colsum   = (float*)(ws + o); o += 1024;
    float* colsumsq = (float*)(ws + o); o += 1024;
    float* scl      = (float*)(ws + o); o += 1024;
    float* shf      = (float*)(ws + o); o += 1024;
    float* cls_acc  = (float*)(ws + o); o += (size_t)NCLS * 256 * 4;
    float* cls_fin  = (float*)(ws + o); o += (size_t)NCLS * 256 * 4;

    hipMemsetAsync(colsum, 0, 2 * 1024, stream);                  // colsum+colsumsq
    hipMemsetAsync(cls_acc, 0, (size_t)NCLS * 256 * 4, stream);   // class accumulator

    gemm1_kernel<<<dim3(2, 1954), 256, 0, stream>>>(point, vox, W1, b1, p2v,
                                                    hbuf, colsum, colsumsq);
    cls_acc_kernel<<<235, 256, 0, stream>>>(logits, vox, cls_acc);
    stats_kernel<<<1, 256, 0, stream>>>(colsum, colsumsq, g1, be1, scl, shf);
    cls_fea2_kernel<<<1, 256, 0, stream>>>(cls_acc, W2, b2, g2, be2, cls_fin);
    gemm2_kernel<<<3907, 256, 0, stream>>>(hbuf, scl, shf, cls_fin, out);
}

// Round 2
// 668.977 us; speedup vs baseline: 1.1849x; 1.1849x over previous
//
#include <hip/hip_runtime.h>
#include <hip/hip_bf16.h>

#define N_PTS 250000
#define N_VOX 60000
#define MID   256
#define KDIM  512
#define NCLS  20
#define BN_EPS 1e-5f

typedef __attribute__((ext_vector_type(8))) short short8;
typedef __attribute__((ext_vector_type(4))) float f32x4;
typedef unsigned int u32;

__device__ __forceinline__ unsigned short f2bf_rne(float f) {
    u32 u = __builtin_bit_cast(u32, f);
    u += 0x7FFFu + ((u >> 16) & 1u);
    return (unsigned short)(u >> 16);
}
// pack two fp32 -> packed bf16 pair (round-half-up): 2 adds + 1 v_perm
__device__ __forceinline__ u32 pack2_rnd(float lo, float hi) {
    u32 a = __builtin_bit_cast(u32, lo) + 0x8000u;
    u32 b = __builtin_bit_cast(u32, hi) + 0x8000u;
    return __builtin_amdgcn_perm(b, a, 0x07060302);   // D = hi16(b)<<16 | hi16(a)
}
__device__ __forceinline__ float bfLo(u32 w) { return __builtin_bit_cast(float, w << 16); }
__device__ __forceinline__ float bfHi(u32 w) { return __builtin_bit_cast(float, w & 0xFFFF0000u); }

// async global -> LDS, 16 bytes per lane (LDS dest must be lane-contiguous)
__device__ __forceinline__ void async_copy16(void* lds, const void* g) {
    __builtin_amdgcn_global_load_lds(
        (const __attribute__((address_space(1))) u32*)g,
        (__attribute__((address_space(3))) u32*)lds, 16, 0, 0);
}

// ---------------------------------------------------------------------------
// prep: W1 fp32 [256][512] -> W1s bf16 in exact MFMA B-fragment layout:
//   frag (kt 0..15, ni 0..15), lane 0..63: short8 = W1[ni*16+(lane&15)][kt*32+(lane>>4)*8 ..]
//   stored at W1s[ ((kt*16+ni)*64 + lane) * 8 ]
// ---------------------------------------------------------------------------
__global__ __launch_bounds__(256) void prep_w1_kernel(
    const float* __restrict__ W1, unsigned short* __restrict__ W1s)
{
    const int idx = blockIdx.x * 256 + threadIdx.x;   // 0..16383
    const int lane = idx & 63;
    const int ni = (idx >> 6) & 15;
    const int kt = idx >> 10;
    const int n = ni * 16 + (lane & 15);
    const int k = kt * 32 + (lane >> 4) * 8;
    const float* src = W1 + (size_t)n * 512 + k;
    unsigned short v[8];
    #pragma unroll
    for (int j = 0; j < 8; ++j) v[j] = f2bf_rne(src[j]);
    ushort4* dst = (ushort4*)(W1s + (size_t)idx * 8);
    dst[0] = make_ushort4(v[0], v[1], v[2], v[3]);
    dst[1] = make_ushort4(v[4], v[5], v[6], v[7]);
}

// ---------------------------------------------------------------------------
// GEMM1: h[250000][256] = concat(point, vox[p2v]) @ W1^T + b1   (bf16 MFMA)
// Tile 128(M) x 256(N=all), BK=32. 256 thr = 4 waves (2x2): wave = 64m x 128n.
// A: fp32 global -> LDS via async global_load_lds (double buffer, 1 barrier/kt),
//    16B-chunk XOR swizzle on the SOURCE address (LDS dest stays lane-linear).
// B: register fragments straight from pre-swizzled W1s (L2-resident).
// fp32->bf16 conversion on the LDS->reg fragment path via v_perm.
// Epilogue: +b1, bf16 store to hbuf, per-column sum/sumsq atomics for BN.
// ---------------------------------------------------------------------------
__global__ __launch_bounds__(256, 2) void gemm1_kernel(
    const float* __restrict__ point, const float* __restrict__ vox,
    const unsigned short* __restrict__ W1s, const float* __restrict__ b1,
    const int* __restrict__ p2v,
    unsigned short* __restrict__ hbuf,
    float* __restrict__ colsum, float* __restrict__ colsumsq)
{
    __shared__ float As[2][128 * 32];   // 2 x 16 KB, unpadded (async-copy layout)

    const int tid = threadIdx.x;
    const int bM = blockIdx.x;
    const int lane = tid & 63;
    const int wv = tid >> 6;
    const int wm = wv & 1;
    const int wn = wv >> 1;
    const int l15 = lane & 15;
    const int l4  = lane >> 4;

    // staging source pointers: load l stages LDS slot idx = l*256+tid
    // (row r = idx>>3, chunk pos pc = idx&7 holds source chunk pc ^ (r&7))
    const float* aP[4];
    const float* aV[4];
    #pragma unroll
    for (int l = 0; l < 4; ++l) {
        const int idx = l * 256 + tid;
        const int r = idx >> 3;
        const int c = (idx & 7) ^ (r & 7);       // swizzled source 16B chunk
        int rg = bM * 128 + r;
        if (rg > N_PTS - 1) rg = N_PTS - 1;
        const int vm = p2v[rg];
        aP[l] = point + (size_t)rg * 256 + c * 4;
        aV[l] = vox   + (size_t)vm * 256 + c * 4;
    }

    f32x4 acc[4][8];
    #pragma unroll
    for (int mi = 0; mi < 4; ++mi)
        #pragma unroll
        for (int j = 0; j < 8; ++j)
            acc[mi][j] = (f32x4){0.f, 0.f, 0.f, 0.f};

    // prologue: stage tile 0 into buf 0
    #pragma unroll
    for (int l = 0; l < 4; ++l)
        async_copy16(&As[0][(l * 256 + tid) * 4], aP[l]);

    #pragma unroll 2
    for (int kt = 0; kt < 16; ++kt) {
        __syncthreads();   // compiler's vmcnt drain completes tile-kt loads (issued last iter)

        // B fragments for this kt (oldest vmcnt entries -> precise wait later)
        short8 bfr[8];
        #pragma unroll
        for (int j = 0; j < 8; ++j) {
            const int ni = wn * 8 + j;
            bfr[j] = *(const short8*)(W1s + ((size_t)(kt * 16 + ni) * 64 + lane) * 8);
        }

        // stage tile kt+1 into the other buffer (stays in flight across compute)
        if (kt < 15) {
            const int kn = kt + 1;
            const int ko = (kn & 7) * 32;
            #pragma unroll
            for (int l = 0; l < 4; ++l) {
                const float* src = (kn < 8) ? (aP[l] + ko) : (aV[l] + ko);
                async_copy16(&As[(kn & 1)][(l * 256 + tid) * 4], src);
            }
        }

        // A fragments: LDS fp32 -> bf16 pack
        const float* buf = As[kt & 1];
        short8 afr[4];
        #pragma unroll
        for (int mi = 0; mi < 4; ++mi) {
            const int m = wm * 64 + mi * 16 + l15;
            const int c0 = (l4 * 2) ^ (m & 7);
            const float* base = buf + m * 32;
            const f32x4 v0 = *(const f32x4*)(base + c0 * 4);          // k = l4*8 + 0..3
            const f32x4 v1 = *(const f32x4*)(base + (c0 ^ 1) * 4);    // k = l4*8 + 4..7
            u32 q[4];
            q[0] = pack2_rnd(v0[0], v0[1]);
            q[1] = pack2_rnd(v0[2], v0[3]);
            q[2] = pack2_rnd(v1[0], v1[1]);
            q[3] = pack2_rnd(v1[2], v1[3]);
            u32* ap = (u32*)&afr[mi];
            ap[0] = q[0]; ap[1] = q[1]; ap[2] = q[2]; ap[3] = q[3];
        }

        #pragma unroll
        for (int mi = 0; mi < 4; ++mi)
            #pragma unroll
            for (int j = 0; j < 8; ++j)
                acc[mi][j] = __builtin_amdgcn_mfma_f32_16x16x32_bf16(
                                 afr[mi], bfr[j], acc[mi][j], 0, 0, 0);
    }

    // epilogue: +b1, bf16 store, BN partial sums
    #pragma unroll
    for (int j = 0; j < 8; ++j) {
        const int colG = wn * 128 + j * 16 + l15;
        const float b1v = b1[colG];
        float s = 0.f, sq = 0.f;
        #pragma unroll
        for (int mi = 0; mi < 4; ++mi) {
            const int rgBase = bM * 128 + wm * 64 + mi * 16 + l4 * 4;
            #pragma unroll
            for (int r = 0; r < 4; ++r) {
                const int rr = rgBase + r;
                if (rr < N_PTS) {
                    const float hv = acc[mi][j][r] + b1v;
                    hbuf[(size_t)rr * 256 + colG] = f2bf_rne(hv);
                    s  += hv;
                    sq += hv * hv;
                }
            }
        }
        s  += __shfl_xor(s, 16);  s  += __shfl_xor(s, 32);
        sq += __shfl_xor(sq, 16); sq += __shfl_xor(sq, 32);
        if (lane < 16) {
            atomicAdd(&colsum[colG], s);
            atomicAdd(&colsumsq[colG], sq);
        }
    }
}

// ---------------------------------------------------------------------------
// cls_acc[c][f] = sum_b softmax(logits)[b][c] * vox[b][f]   (unchanged, known good)
// ---------------------------------------------------------------------------
#define NCHUNK 938
__global__ __launch_bounds__(256) void cls_acc_kernel(
    const float* __restrict__ logits, const float* __restrict__ vox,
    float* __restrict__ cls_acc)
{
    __shared__ float probs[64 * 24];
    const int tid = threadIdx.x;
    float acc[NCLS];
    #pragma unroll
    for (int c = 0; c < NCLS; ++c) acc[c] = 0.f;

    for (int ci = 0; ci < 4; ++ci) {
        const int chunk = blockIdx.x * 4 + ci;
        if (chunk >= NCHUNK) break;
        const int v0 = chunk * 64;
        __syncthreads();
        if (tid < 64) {
            const int v = v0 + tid;
            if (v < N_VOX) {
                float l[NCLS];
                float mx = -1e30f;
                #pragma unroll
                for (int c = 0; c < NCLS; ++c) {
                    l[c] = logits[(size_t)v * NCLS + c];
                    mx = fmaxf(mx, l[c]);
                }
                float sum = 0.f;
                #pragma unroll
                for (int c = 0; c < NCLS; ++c) { l[c] = __expf(l[c] - mx); sum += l[c]; }
                const float inv = 1.f / sum;
                #pragma unroll
                for (int c = 0; c < NCLS; ++c) probs[tid * 24 + c] = l[c] * inv;
            }
        }
        __syncthreads();
        const int nb = min(64, N_VOX - v0);
        for (int b = 0; b < nb; ++b) {
            const float vv = vox[(size_t)(v0 + b) * 256 + tid];
            #pragma unroll
            for (int c4 = 0; c4 < 5; ++c4) {
                const float4 p = *(const float4*)&probs[b * 24 + c4 * 4];
                acc[c4 * 4 + 0] += p.x * vv;
                acc[c4 * 4 + 1] += p.y * vv;
                acc[c4 * 4 + 2] += p.z * vv;
                acc[c4 * 4 + 3] += p.w * vv;
            }
        }
    }
    #pragma unroll
    for (int c = 0; c < NCLS; ++c)
        atomicAdd(&cls_acc[c * 256 + tid], acc[c]);
}

// ---------------------------------------------------------------------------
// fuse: BN1 stats -> scl/shf; cls_fin = BN20(cls_acc@W2^T+b2); bake cls_fin
// into bf16 MFMA B-fragment layout: frag (kt 0..7, ni 0..1), lane:
//   short8 = cls_fin[ni*16+(lane&15)][kt*32+(lane>>4)*8..]   (n>=20 -> 0)
// ---------------------------------------------------------------------------
__global__ __launch_bounds__(256) void fuse_kernel(
    const float* __restrict__ colsum, const float* __restrict__ colsumsq,
    const float* __restrict__ g1, const float* __restrict__ be1,
    float* __restrict__ scl, float* __restrict__ shf,
    const float* __restrict__ cls_acc, const float* __restrict__ W2,
    const float* __restrict__ b2, const float* __restrict__ g2,
    const float* __restrict__ be2, unsigned short* __restrict__ cls_frag)
{
    __shared__ float cf[NCLS * 256];
    __shared__ float cf2[NCLS * 256];
    const int tid = threadIdx.x;

    // BN1 stats
    {
        const float mean = colsum[tid] * (1.0f / N_PTS);
        const float var  = colsumsq[tid] * (1.0f / N_PTS) - mean * mean;
        const float sc = g1[tid] * rsqrtf(var + BN_EPS);
        scl[tid] = sc;
        shf[tid] = be1[tid] - mean * sc;
    }

    for (int i = tid; i < NCLS * 256; i += 256) cf[i] = cls_acc[i];
    __syncthreads();

    float acc[NCLS];
    #pragma unroll
    for (int c = 0; c < NCLS; ++c) acc[c] = b2[tid];
    for (int k = 0; k < 256; k += 4) {
        const float4 w = *(const float4*)&W2[(size_t)tid * 256 + k];
        #pragma unroll
        for (int c = 0; c < NCLS; ++c) {
            const float4 f = *(const float4*)&cf[c * 256 + k];
            acc[c] += w.x * f.x + w.y * f.y + w.z * f.z + w.w * f.w;
        }
    }
    float mean = 0.f;
    #pragma unroll
    for (int c = 0; c < NCLS; ++c) mean += acc[c];
    mean *= (1.f / NCLS);
    float var = 0.f;
    #pragma unroll
    for (int c = 0; c < NCLS; ++c) { const float d = acc[c] - mean; var += d * d; }
    var *= (1.f / NCLS);
    const float sc = g2[tid] * rsqrtf(var + BN_EPS);
    const float bb = be2[tid];
    #pragma unroll
    for (int c = 0; c < NCLS; ++c)
        cf2[c * 256 + tid] = (acc[c] - mean) * sc + bb;
    __syncthreads();

    // bake B fragments for GEMM2
    #pragma unroll
    for (int i = 0; i < 4; ++i) {
        const int idx = i * 256 + tid;       // 0..1023
        const int lane = idx & 63;
        const int ni = (idx >> 6) & 1;
        const int kt = idx >> 7;
        const int n = ni * 16 + (lane & 15);
        const int k = kt * 32 + (lane >> 4) * 8;
        unsigned short v[8];
        #pragma unroll
        for (int j = 0; j < 8; ++j)
            v[j] = (n < NCLS) ? f2bf_rne(cf2[n * 256 + k + j]) : (unsigned short)0;
        ushort4* dst = (ushort4*)(cls_frag + (size_t)idx * 8);
        dst[0] = make_ushort4(v[0], v[1], v[2], v[3]);
        dst[1] = make_ushort4(v[4], v[5], v[6], v[7]);
    }
}

// ---------------------------------------------------------------------------
// GEMM2: out[i][c] = relu(h[i]*scl+shf) @ cls_fin^T   (bf16 MFMA, no barriers
// in K-loop). Block = 256 rows, 4 waves x 64 rows; N padded to 32 (2 frags).
// A-frags straight from global hbuf (64B/row segments), BN+ReLU in registers.
// ---------------------------------------------------------------------------
__global__ __launch_bounds__(256) void gemm2_kernel(
    const unsigned short* __restrict__ hbuf,
    const float* __restrict__ scl, const float* __restrict__ shf,
    const unsigned short* __restrict__ cls_frag,
    float* __restrict__ out)
{
    __shared__ float sS[256], sT[256];
    const int tid = threadIdx.x;
    sS[tid] = scl[tid];
    sT[tid] = shf[tid];
    __syncthreads();

    const int lane = tid & 63;
    const int w = tid >> 6;
    const int l15 = lane & 15;
    const int l4 = lane >> 4;
    const int mBase = blockIdx.x * 256 + w * 64;

    f32x4 acc[4][2];
    #pragma unroll
    for (int mi = 0; mi < 4; ++mi) {
        acc[mi][0] = (f32x4){0.f, 0.f, 0.f, 0.f};
        acc[mi][1] = (f32x4){0.f, 0.f, 0.f, 0.f};
    }

    #pragma unroll
    for (int kt = 0; kt < 8; ++kt) {
        const int k0 = kt * 32 + l4 * 8;
        const short8 bf0 = *(const short8*)(cls_frag + ((kt * 2 + 0) * 64 + lane) * 8);
        const short8 bf1 = *(const short8*)(cls_frag + ((kt * 2 + 1) * 64 + lane) * 8);
        const f32x4 s0 = *(const f32x4*)&sS[k0];
        const f32x4 s1 = *(const f32x4*)&sS[k0 + 4];
        const f32x4 t0 = *(const f32x4*)&sT[k0];
        const f32x4 t1 = *(const f32x4*)&sT[k0 + 4];
        const float sv[8] = {s0[0], s0[1], s0[2], s0[3], s1[0], s1[1], s1[2], s1[3]};
        const float tv[8] = {t0[0], t0[1], t0[2], t0[3], t1[0], t1[1], t1[2], t1[3]};

        #pragma unroll
        for (int mi = 0; mi < 4; ++mi) {
            int m = mBase + mi * 16 + l15;
            if (m > N_PTS - 1) m = N_PTS - 1;
            const uint4 hx = *(const uint4*)(hbuf + (size_t)m * 256 + k0);
            const u32 wd[4] = {hx.x, hx.y, hx.z, hx.w};
            short8 a;
            u32* ap = (u32*)&a;
            #pragma unroll
            for (int p = 0; p < 4; ++p) {
                const float x0 = fmaxf(fmaf(bfLo(wd[p]), sv[2 * p],     tv[2 * p]),     0.f);
                const float x1 = fmaxf(fmaf(bfHi(wd[p]), sv[2 * p + 1], tv[2 * p + 1]), 0.f);
                ap[p] = pack2_rnd(x0, x1);
            }
            acc[mi][0] = __builtin_amdgcn_mfma_f32_16x16x32_bf16(a, bf0, acc[mi][0], 0, 0, 0);
            acc[mi][1] = __builtin_amdgcn_mfma_f32_16x16x32_bf16(a, bf1, acc[mi][1], 0, 0, 0);
        }
    }

    #pragma unroll
    for (int mi = 0; mi < 4; ++mi) {
        #pragma unroll
        for (int ni = 0; ni < 2; ++ni) {
            const int n = ni * 16 + l15;
            #pragma unroll
            for (int r = 0; r < 4; ++r) {
                const int m = mBase + mi * 16 + l4 * 4 + r;
                if (n < NCLS && m < N_PTS)
                    out[(size_t)m * 20 + n] = acc[mi][ni][r];
            }
        }
    }
}

// ---------------------------------------------------------------------------
extern "C" void kernel_launch(void* const* d_in, const int* in_sizes, int n_in,
                              void* d_out, int out_size, void* d_ws, size_t ws_size,
                              hipStream_t stream)
{
    const float* point  = (const float*)d_in[0];
    const float* vox    = (const float*)d_in[1];
    const float* logits = (const float*)d_in[2];
    const float* W1     = (const float*)d_in[3];
    const float* b1     = (const float*)d_in[4];
    const float* g1     = (const float*)d_in[5];
    const float* be1    = (const float*)d_in[6];
    const float* W2     = (const float*)d_in[7];
    const float* b2     = (const float*)d_in[8];
    const float* g2     = (const float*)d_in[9];
    const float* be2    = (const float*)d_in[10];
    const int*   p2v    = (const int*)d_in[11];
    float* out = (float*)d_out;

    char* ws = (char*)d_ws;
    unsigned short* hbuf = (unsigned short*)ws;
    size_t o = (size_t)N_PTS * 256 * 2;               // 128,000,000 B
    float* colsum   = (float*)(ws + o); o += 1024;
    float* colsumsq = (float*)(ws + o); o += 1024;
    float* scl      = (float*)(ws + o); o += 1024;
    float* shf      = (float*)(ws + o); o += 1024;
    float* cls_acc  = (float*)(ws + o); o += (size_t)NCLS * 256 * 4;
    unsigned short* W1s      = (unsigned short*)(ws + o); o += (size_t)16384 * 8 * 2;  // 256 KB
    unsigned short* cls_frag = (unsigned short*)(ws + o); o += (size_t)1024 * 8 * 2;   // 16 KB

    hipMemsetAsync(colsum, 0, 2 * 1024, stream);
    hipMemsetAsync(cls_acc, 0, (size_t)NCLS * 256 * 4, stream);

    prep_w1_kernel<<<64, 256, 0, stream>>>(W1, W1s);
    gemm1_kernel<<<1954, 256, 0, stream>>>(point, vox, W1s, b1, p2v,
                                           hbuf, colsum, colsumsq);
    cls_acc_kernel<<<235, 256, 0, stream>>>(logits, vox, cls_acc);
    fuse_kernel<<<1, 256, 0, stream>>>(colsum, colsumsq, g1, be1, scl, shf,
                                       cls_acc, W2, b2, g2, be2, cls_frag);
    gemm2_kernel<<<977, 256, 0, stream>>>(hbuf, scl, shf, cls_frag, out);
}